// Round 5
// baseline (1480.807 us; speedup 1.0000x reference)
//
#include <hip/hip_runtime.h>

typedef unsigned short u16;
typedef unsigned int   u32;
typedef __attribute__((ext_vector_type(8))) short short8;
typedef __attribute__((ext_vector_type(4))) float f32x4;

#define DD      768
#define KK      6144   /* 8*768 : [root | W0..W6] concatenated on K */
#define NREL    7
#define NLAYERS 5

__device__ __forceinline__ float b2f(u16 v) {
  return __uint_as_float(((u32)v) << 16);
}
__device__ __forceinline__ u16 f2bf(float f) {
  u32 x = __float_as_uint(f);
  x += 0x7fffu + ((x >> 16) & 1u);
  return (u16)(x >> 16);
}
__device__ __forceinline__ void gload16(const void* g, void* l) {
  __builtin_amdgcn_global_load_lds(
      (const __attribute__((address_space(1))) void*)g,
      (__attribute__((address_space(3))) void*)l, 16, 0, 0);
}

// ---------- setup kernels ----------

__global__ void cast_x_kernel(const float* __restrict__ x, u16* __restrict__ H, size_t n) {
  for (size_t i = ((size_t)blockIdx.x * 256 + threadIdx.x) * 4; i < n; i += (size_t)gridDim.x * 256 * 4) {
    float4 v = *(const float4*)&x[i];
    u32 lo = (u32)f2bf(v.x) | ((u32)f2bf(v.y) << 16);
    u32 hi = (u32)f2bf(v.z) | ((u32)f2bf(v.w) << 16);
    uint2 o; o.x = lo; o.y = hi;
    *(uint2*)&H[i] = o;
  }
}

__global__ void count_kernel(const int* __restrict__ eidx, const int* __restrict__ etype,
                             int* cnt_dst, int* cnt_rel, int E, int Nn) {
  int e = blockIdx.x * 256 + threadIdx.x;
  if (e >= E) return;
  int dst = eidx[E + e];
  int rel = etype[e] + 1;
  atomicAdd(&cnt_dst[dst], 1);
  atomicAdd(&cnt_rel[(size_t)rel * Nn + dst], 1);
}

__global__ __launch_bounds__(1024) void scan_kernel(const int* __restrict__ cnt, int* __restrict__ offs, int n) {
  __shared__ int part[1024];
  int t = threadIdx.x;
  int per = (n + 1023) / 1024;
  int base = t * per;
  int s = 0;
  for (int i = 0; i < per; ++i) { int idx = base + i; if (idx < n) s += cnt[idx]; }
  part[t] = s;
  __syncthreads();
  for (int o = 1; o < 1024; o <<= 1) {
    int v = (t >= o) ? part[t - o] : 0;
    __syncthreads();
    part[t] += v;
    __syncthreads();
  }
  int excl = (t == 0) ? 0 : part[t - 1];
  s = excl;
  for (int i = 0; i < per; ++i) { int idx = base + i; if (idx < n) { offs[idx] = s; s += cnt[idx]; } }
  if (t == 1023) offs[n] = part[1023];
}

__global__ void fillperm_kernel(const int* __restrict__ eidx, const int* __restrict__ offs,
                                int* fill, int* perm, int E) {
  int e = blockIdx.x * 256 + threadIdx.x;
  if (e >= E) return;
  int dst = eidx[E + e];
  int pos = offs[dst] + atomicAdd(&fill[dst], 1);
  perm[pos] = e;
}

// Per-layer weight conversion: Bt[n][seg*768+kk] = bf16( seg==0 ? roots[kk][n] : W[seg-1][kk][n] )
__global__ void wcat_kernel(const float* __restrict__ W, const float* __restrict__ R, u16* __restrict__ Bt) {
  __shared__ float t[32 * 33];
  int b = blockIdx.x;
  int s = b / 576, rem = b % 576;
  int kt = rem / 24, nt = rem % 24;
  const float* src = (s == 0) ? R : (W + (size_t)(s - 1) * DD * DD);
  int tj = threadIdx.x & 31, ti = threadIdx.x >> 5;  // ti 0..7
#pragma unroll
  for (int i = 0; i < 4; ++i) {
    int kk = kt * 32 + ti + i * 8;
    t[(ti + i * 8) * 33 + tj] = src[(size_t)kk * DD + nt * 32 + tj];
  }
  __syncthreads();
#pragma unroll
  for (int i = 0; i < 4; ++i) {
    int nn_ = nt * 32 + ti + i * 8;
    Bt[(size_t)nn_ * KK + (size_t)s * DD + kt * 32 + tj] = f2bf(t[tj * 33 + ti + i * 8]);
  }
}

// One block (192 thr) per destination node. rel is wave-uniform per edge ->
// accumulate into per-thread registers via a 7-way switch; no LDS, no syncs.
// Also copies own row Hin[v] into segment 0 (fused former copy_h).
__global__ __launch_bounds__(192) void aggregate_kernel(
    const u16* __restrict__ H, const int* __restrict__ esrc, const int* __restrict__ etype,
    const int* __restrict__ offs, const int* __restrict__ perm, const int* __restrict__ cnt_rel,
    u16* __restrict__ Acat, int node0, int Nn) {
  int v = node0 + blockIdx.x;
  int t = threadIdx.x;
  int j0 = t * 4;  // 192*4 = 768
  size_t rowbase = (size_t)blockIdx.x * KK;
  // segment 0: copy own row
  *(uint2*)&Acat[rowbase + j0] = *(const uint2*)&H[(size_t)v * DD + j0];
  float a0[4] = {0,0,0,0}, a1[4] = {0,0,0,0}, a2[4] = {0,0,0,0}, a3[4] = {0,0,0,0};
  float a4[4] = {0,0,0,0}, a5[4] = {0,0,0,0}, a6[4] = {0,0,0,0};
  int beg = offs[v], end = offs[v + 1];
  for (int e = beg; e < end; ++e) {
    int eid = perm[e];
    int src = esrc[eid];
    int rel = etype[eid] + 1;
    uint2 w = *(const uint2*)&H[(size_t)src * DD + j0];
    float f0 = b2f((u16)(w.x & 0xffff));
    float f1 = b2f((u16)(w.x >> 16));
    float f2 = b2f((u16)(w.y & 0xffff));
    float f3 = b2f((u16)(w.y >> 16));
    switch (rel) {
      case 0: a0[0]+=f0; a0[1]+=f1; a0[2]+=f2; a0[3]+=f3; break;
      case 1: a1[0]+=f0; a1[1]+=f1; a1[2]+=f2; a1[3]+=f3; break;
      case 2: a2[0]+=f0; a2[1]+=f1; a2[2]+=f2; a2[3]+=f3; break;
      case 3: a3[0]+=f0; a3[1]+=f1; a3[2]+=f2; a3[3]+=f3; break;
      case 4: a4[0]+=f0; a4[1]+=f1; a4[2]+=f2; a4[3]+=f3; break;
      case 5: a5[0]+=f0; a5[1]+=f1; a5[2]+=f2; a5[3]+=f3; break;
      default: a6[0]+=f0; a6[1]+=f1; a6[2]+=f2; a6[3]+=f3; break;
    }
  }
  const float* regs[NREL] = {a0, a1, a2, a3, a4, a5, a6};
#pragma unroll
  for (int r = 0; r < NREL; ++r) {
    int c = cnt_rel[(size_t)r * Nn + v];
    float inv = (c > 0) ? 1.f / (float)c : 0.f;
    const float* a = regs[r];
    u32 lo = (u32)f2bf(a[0] * inv) | ((u32)f2bf(a[1] * inv) << 16);
    u32 hi = (u32)f2bf(a[2] * inv) | ((u32)f2bf(a[3] * inv) << 16);
    uint2 o; o.x = lo; o.y = hi;
    *(uint2*)&Acat[rowbase + (size_t)(r + 1) * DD + j0] = o;
  }
}

// ---------- 256x256 8-wave GEMM, m201 8-phase template port ----------
// BK=64, 2 LDS slots x (A 32KB + B 32KB) = 128 KB, XOR swizzle byte^=(row&7)<<4,
// 4 phases/K-tile: reads {12,8,4,0} consumed same-phase after bar+lgkmcnt(0);
// distance-1 prefetch (A in P0, B in P1), vmcnt(0) once per tile at P3.

#define MFMA_(a_, b_, c_) __builtin_amdgcn_mfma_f32_16x16x32_bf16(a_, b_, c_, 0, 0, 0)

__global__ __launch_bounds__(512, 2) void gemm256_kernel(
    const u16* __restrict__ A, const u16* __restrict__ Bt, const float* __restrict__ bias,
    u16* __restrict__ Hout, float* __restrict__ Cout, int Mvalid, int Mtiles) {
  // [slot][A=0/B=1][32KB] ; row = 128 bytes (64 bf16)
  __shared__ u16 sm[2][2][16384];

  int tid = threadIdx.x;
  int lane = tid & 63;
  int wv = tid >> 6;            // 0..7
  int wm = wv >> 2, wn = wv & 3;

  // XCD-bijective block swizzle (m204), bn fastest so same-XCD blocks share A panels
  int nwg = Mtiles * 3;
  int orig = (int)blockIdx.x;
  int q8 = nwg >> 3, r8 = nwg & 7;
  int xcd = orig & 7, rank = orig >> 3;
  int wg = (xcd < r8 ? xcd * (q8 + 1) : r8 * (q8 + 1) + (xcd - r8) * q8) + rank;
  int bm = wg / 3, bn = wg % 3;

  // ---- staging: linear LDS dest, inverse-swizzled global source (rule #21) ----
  // linear byte q = j*8192 + tid*16 -> row = j*64 + (tid>>3), chunk' = tid&7,
  // source chunk = (tid&7) ^ (row&7) = (tid&7) ^ ((tid>>3)&7)
  int srow = tid >> 3;
  int sc = (tid & 7) ^ (srow & 7);
  const char* gA0 = (const char*)A  + (size_t)(bm * 256 + srow) * (KK * 2) + sc * 16;
  const char* gB0 = (const char*)Bt + (size_t)(bn * 256 + srow) * (KK * 2) + sc * 16;
  const size_t JSTRIDE = (size_t)64 * KK * 2;  // 64 rows

  // ---- swizzled ds_read lane offsets: byte = row*128 + ((c ^ (row&7))*16),
  // row&7 == rsel&7 for all frag rows (wave/m parts are multiples of 8/16)
  int rsel = lane & 15, kq = lane >> 4;
  int off0 = rsel * 128 + (((kq)     ^ (rsel & 7)) * 16);
  int off1 = rsel * 128 + (((kq + 4) ^ (rsel & 7)) * 16);

  f32x4 acc[8][4];
#pragma unroll
  for (int m = 0; m < 8; ++m)
#pragma unroll
    for (int n = 0; n < 4; ++n) acc[m][n] = (f32x4){0.f, 0.f, 0.f, 0.f};

  const int NKT = KK / 64;  // 96 K-tiles

  // prologue: stage tile 0 into slot 0, drain, barrier
#pragma unroll
  for (int j = 0; j < 4; ++j)
    gload16(gA0 + (size_t)j * JSTRIDE, (char*)&sm[0][0][0] + j * 8192 + tid * 16);
#pragma unroll
  for (int j = 0; j < 4; ++j)
    gload16(gB0 + (size_t)j * JSTRIDE, (char*)&sm[0][1][0] + j * 8192 + tid * 16);
  asm volatile("s_waitcnt vmcnt(0)" ::: "memory");
  __builtin_amdgcn_s_barrier();
  __builtin_amdgcn_sched_barrier(0);

  for (int t = 0; t < NKT; ++t) {
    int s = t & 1;
    const char* aB = (const char*)&sm[s][0][0];
    const char* bB = (const char*)&sm[s][1][0];
    char* aN = (char*)&sm[s ^ 1][0][0];
    char* bN = (char*)&sm[s ^ 1][1][0];
    size_t ko = (size_t)(t + 1) * 128;
    int more = (t + 1 < NKT);

    short8 a03[4][2], a47[4][2], bb[2][2];

    // ======== P0: read a03 (8) + b01 (4); stage A(t+1); MFMA Q0 = m0-3 x n0-1 ========
#pragma unroll
    for (int m = 0; m < 4; ++m) {
      a03[m][0] = *(const short8*)(aB + (wm * 128 + m * 16) * 128 + off0);
      a03[m][1] = *(const short8*)(aB + (wm * 128 + m * 16) * 128 + off1);
    }
#pragma unroll
    for (int n = 0; n < 2; ++n) {
      bb[n][0] = *(const short8*)(bB + (wn * 64 + n * 16) * 128 + off0);
      bb[n][1] = *(const short8*)(bB + (wn * 64 + n * 16) * 128 + off1);
    }
    if (more) {
#pragma unroll
      for (int j = 0; j < 4; ++j)
        gload16(gA0 + (size_t)j * JSTRIDE + ko, aN + j * 8192 + tid * 16);
    }
    asm volatile("s_waitcnt lgkmcnt(8)" ::: "memory");  // early-drain hint (12-read phase)
    __builtin_amdgcn_s_barrier();
    asm volatile("s_waitcnt lgkmcnt(0)" ::: "memory");
    __builtin_amdgcn_sched_barrier(0);
    __builtin_amdgcn_s_setprio(1);
#pragma unroll
    for (int m = 0; m < 4; ++m)
#pragma unroll
      for (int n = 0; n < 2; ++n) {
        acc[m][n] = MFMA_(a03[m][0], bb[n][0], acc[m][n]);
        acc[m][n] = MFMA_(a03[m][1], bb[n][1], acc[m][n]);
      }
    __builtin_amdgcn_s_setprio(0);
    __builtin_amdgcn_s_barrier();

    // ======== P1: read a47 (8); stage B(t+1); MFMA Q1 = m4-7 x n0-1 ========
#pragma unroll
    for (int m = 0; m < 4; ++m) {
      a47[m][0] = *(const short8*)(aB + (wm * 128 + (m + 4) * 16) * 128 + off0);
      a47[m][1] = *(const short8*)(aB + (wm * 128 + (m + 4) * 16) * 128 + off1);
    }
    if (more) {
#pragma unroll
      for (int j = 0; j < 4; ++j)
        gload16(gB0 + (size_t)j * JSTRIDE + ko, bN + j * 8192 + tid * 16);
    }
    __builtin_amdgcn_s_barrier();
    asm volatile("s_waitcnt lgkmcnt(0)" ::: "memory");
    __builtin_amdgcn_sched_barrier(0);
    __builtin_amdgcn_s_setprio(1);
#pragma unroll
    for (int m = 0; m < 4; ++m)
#pragma unroll
      for (int n = 0; n < 2; ++n) {
        acc[m + 4][n] = MFMA_(a47[m][0], bb[n][0], acc[m + 4][n]);
        acc[m + 4][n] = MFMA_(a47[m][1], bb[n][1], acc[m + 4][n]);
      }
    __builtin_amdgcn_s_setprio(0);
    __builtin_amdgcn_s_barrier();

    // ======== P2: read b23 (4, reuse bb); MFMA Q2 = m4-7 x n2-3 ========
#pragma unroll
    for (int n = 0; n < 2; ++n) {
      bb[n][0] = *(const short8*)(bB + (wn * 64 + (n + 2) * 16) * 128 + off0);
      bb[n][1] = *(const short8*)(bB + (wn * 64 + (n + 2) * 16) * 128 + off1);
    }
    __builtin_amdgcn_s_barrier();
    asm volatile("s_waitcnt lgkmcnt(0)" ::: "memory");
    __builtin_amdgcn_sched_barrier(0);
    __builtin_amdgcn_s_setprio(1);
#pragma unroll
    for (int m = 0; m < 4; ++m)
#pragma unroll
      for (int n = 0; n < 2; ++n) {
        acc[m + 4][n + 2] = MFMA_(a47[m][0], bb[n][0], acc[m + 4][n + 2]);
        acc[m + 4][n + 2] = MFMA_(a47[m][1], bb[n][1], acc[m + 4][n + 2]);
      }
    __builtin_amdgcn_s_setprio(0);
    __builtin_amdgcn_s_barrier();

    // ======== P3: no reads; MFMA Q3 = m0-3 x n2-3; vmcnt(0); bar ========
    __builtin_amdgcn_s_setprio(1);
#pragma unroll
    for (int m = 0; m < 4; ++m)
#pragma unroll
      for (int n = 0; n < 2; ++n) {
        acc[m][n + 2] = MFMA_(a03[m][0], bb[n][0], acc[m][n + 2]);
        acc[m][n + 2] = MFMA_(a03[m][1], bb[n][1], acc[m][n + 2]);
      }
    __builtin_amdgcn_s_setprio(0);
    asm volatile("s_waitcnt vmcnt(0)" ::: "memory");
    __builtin_amdgcn_s_barrier();
    __builtin_amdgcn_sched_barrier(0);
  }

  // ---- epilogue: bias + ReLU, write bf16 h_next / f32 out ----
  int rif = (lane >> 4) * 4;
  int cidx = lane & 15;
#pragma unroll
  for (int m = 0; m < 8; ++m) {
    int rl = bm * 256 + wm * 128 + m * 16 + rif;
#pragma unroll
    for (int n = 0; n < 4; ++n) {
      int c = bn * 256 + wn * 64 + n * 16 + cidx;
      float bv = bias[c];
#pragma unroll
      for (int j = 0; j < 4; ++j) {
        int r = rl + j;
        if (r < Mvalid) {
          float v = acc[m][n][j] + bv;
          v = v > 0.f ? v : 0.f;
          if (Hout) Hout[(size_t)r * DD + c] = f2bf(v);
          if (Cout) Cout[(size_t)r * DD + c] = v;
        }
      }
    }
  }
}

// ---------- host ----------

static inline size_t alignup(size_t x, size_t a) { return (x + a - 1) & ~(a - 1); }

extern "C" void kernel_launch(void* const* d_in, const int* in_sizes, int n_in,
                              void* d_out, int out_size, void* d_ws, size_t ws_size,
                              hipStream_t stream) {
  const float* x       = (const float*)d_in[0];
  const int*   eidx    = (const int*)d_in[1];
  const int*   etype   = (const int*)d_in[2];
  const float* weights = (const float*)d_in[3];
  const float* roots   = (const float*)d_in[4];
  const float* biases  = (const float*)d_in[5];
  float* out = (float*)d_out;

  const int Nn = in_sizes[0] / DD;  // 20000
  const int E  = in_sizes[2];       // 100000

  char* p = (char*)d_ws;
  size_t off = 0;
  auto carve = [&](size_t bytes) -> char* {
    char* r = p + off;
    off = alignup(off + bytes, 256);
    return r;
  };
  u16* H0      = (u16*)carve((size_t)Nn * DD * 2);
  u16* Bt      = (u16*)carve((size_t)DD * KK * 2);
  int* cnt_rel = (int*)carve((size_t)NREL * Nn * 4);
  int* cnt_dst = (int*)carve((size_t)Nn * 4);
  int* offs    = (int*)carve((size_t)(Nn + 1) * 4);
  int* fill    = (int*)carve((size_t)Nn * 4);
  int* perm    = (int*)carve((size_t)E * 4);

  size_t rem = (ws_size > off) ? (ws_size - off) : 0;
  int McCap = (int)(rem / ((size_t)KK * 2));
  int Mpad = ((Nn + 255) / 256) * 256;
  int Mc = (McCap < Mpad) ? (McCap & ~255) : Mpad;
  if (Mc < 256) return;  // workspace too small — fail visibly rather than corrupt
  u16* Acat = (u16*)(p + off);
  int nchunks = (Nn + Mc - 1) / Mc;
  u16* H1 = (u16*)d_out;  // bf16 ping buffer inside d_out (out_size*4 >= Nn*DD*2)

  (void)hipMemsetAsync(cnt_rel, 0, (size_t)NREL * Nn * 4, stream);
  (void)hipMemsetAsync(cnt_dst, 0, (size_t)Nn * 4, stream);
  (void)hipMemsetAsync(fill, 0, (size_t)Nn * 4, stream);

  int eg = (E + 255) / 256;
  count_kernel<<<eg, 256, 0, stream>>>(eidx, etype, cnt_dst, cnt_rel, E, Nn);
  scan_kernel<<<1, 1024, 0, stream>>>(cnt_dst, offs, Nn);
  fillperm_kernel<<<eg, 256, 0, stream>>>(eidx, offs, fill, perm, E);
  cast_x_kernel<<<2048, 256, 0, stream>>>(x, H0, (size_t)Nn * DD);

  const u16* Hin = H0;
  u16* Hnext = H1;
  for (int l = 0; l < NLAYERS; ++l) {
    wcat_kernel<<<8 * 576, 256, 0, stream>>>(weights + (size_t)l * NREL * DD * DD,
                                             roots + (size_t)l * DD * DD, Bt);
    for (int c = 0; c < nchunks; ++c) {
      int node0 = c * Mc;
      int nn = (Nn - node0 < Mc) ? (Nn - node0) : Mc;
      aggregate_kernel<<<nn, 192, 0, stream>>>(Hin, eidx, etype, offs, perm, cnt_rel,
                                               Acat, node0, Nn);
      int mt = (nn + 255) / 256;
      u16* ho = (l < NLAYERS - 1) ? (Hnext + (size_t)node0 * DD) : nullptr;
      float* co = (l == NLAYERS - 1) ? (out + (size_t)node0 * DD) : nullptr;
      gemm256_kernel<<<mt * 3, 512, 0, stream>>>(Acat, Bt, biases + (size_t)l * DD, ho, co, nn, mt);
    }
    const u16* t_ = Hin;
    Hin = Hnext;
    Hnext = (u16*)t_;
  }
}